// Round 3
// baseline (587.329 us; speedup 1.0000x reference)
//
#include <hip/hip_runtime.h>
#include <hip/hip_bf16.h>
#include <hip/hip_fp16.h>

typedef _Float16 half8 __attribute__((ext_vector_type(8)));
typedef _Float16 half4 __attribute__((ext_vector_type(4)));
typedef __fp16 fp16x2 __attribute__((ext_vector_type(2)));
typedef float floatx4 __attribute__((ext_vector_type(4)));

#define HID 128
#define TILE_M 64

__device__ __forceinline__ float fast_silu(float v) {
    float e = __expf(-v);
    return v * __builtin_amdgcn_rcpf(1.f + e);
}

__device__ __forceinline__ unsigned int pk2(float a, float b) {
    fp16x2 h = __builtin_amdgcn_cvt_pkrtz(a, b);
    return __builtin_bit_cast(unsigned int, h);
}

// LDS-only barrier: drains LDS ops but leaves global (vmcnt) traffic in
// flight. Use ONLY where the barrier guards LDS-LDS hazards exclusively.
__device__ __forceinline__ void barrier_lds_only() {
    asm volatile("s_waitcnt lgkmcnt(0)\n\ts_barrier" ::: "memory");
}

// ---------------------------------------------------------------------------
// Kernel 1: node_emb = [x|pos|0-pad] @ [Wa;Wp;0] + (ba+bp). Block handles a
// 64-node tile via MFMA; output assembled in padded LDS, stored coalesced.
// ---------------------------------------------------------------------------
#define LDO 136
__global__ __launch_bounds__(256) void node_emb_kernel(
    const float* __restrict__ x, const float* __restrict__ pos,
    const float* __restrict__ Wa, const float* __restrict__ ba,
    const float* __restrict__ Wp, const float* __restrict__ bp,
    _Float16* __restrict__ nodeEmb, int N)
{
    __shared__ __align__(16) _Float16 sOut[64 * LDO];   // 17 KB
    const int t    = threadIdx.x;
    const int wave = t >> 6;
    const int lane = t & 63;
    const int quad = lane >> 4;
    const int l16  = lane & 15;

    half8 wf[2];
    floatx4 bias[2];
    #pragma unroll
    for (int ct = 0; ct < 2; ++ct) {
        int col = wave * 32 + ct * 16 + l16;
        #pragma unroll
        for (int j = 0; j < 8; ++j) {
            int k = quad * 8 + j;
            float w = 0.f;
            if (k < 16) w = Wa[k * HID + col];
            else if (k < 19) w = Wp[(k - 16) * HID + col];
            wf[ct][j] = (_Float16)w;
        }
        #pragma unroll
        for (int i = 0; i < 4; ++i) {
            int c2 = wave * 32 + ct * 16 + quad * 4 + i;
            bias[ct][i] = ba[c2] + bp[c2];
        }
    }

    int nTiles = (N + 63) >> 6;
    for (int tile = blockIdx.x; tile < nTiles; tile += gridDim.x) {
        int base = tile * 64;
        half8 af[4];
        #pragma unroll
        for (int rt = 0; rt < 4; ++rt) {
            int node = base + rt * 16 + l16;
            int nd = node < N ? node : N - 1;
            half8 a = (half8){0, 0, 0, 0, 0, 0, 0, 0};
            if (quad < 2) {
                const float* xp = x + (size_t)nd * 16 + quad * 8;
                float4 v0 = *(const float4*)xp;
                float4 v1 = *(const float4*)(xp + 4);
                a[0] = (_Float16)v0.x; a[1] = (_Float16)v0.y;
                a[2] = (_Float16)v0.z; a[3] = (_Float16)v0.w;
                a[4] = (_Float16)v1.x; a[5] = (_Float16)v1.y;
                a[6] = (_Float16)v1.z; a[7] = (_Float16)v1.w;
            } else if (quad == 2) {
                const float* pp = pos + (size_t)nd * 3;
                a[0] = (_Float16)pp[0]; a[1] = (_Float16)pp[1]; a[2] = (_Float16)pp[2];
            }
            af[rt] = a;
        }
        #pragma unroll
        for (int ct = 0; ct < 2; ++ct)
            #pragma unroll
            for (int rt = 0; rt < 4; ++rt) {
                floatx4 d = bias[ct];
                d = __builtin_amdgcn_mfma_f32_16x16x32_f16(wf[ct], af[rt], d, 0, 0, 0);
                half4 hv;
                hv[0] = (_Float16)d[0]; hv[1] = (_Float16)d[1];
                hv[2] = (_Float16)d[2]; hv[3] = (_Float16)d[3];
                *(half4*)&sOut[(rt * 16 + l16) * LDO + wave * 32 + ct * 16 + quad * 4] = hv;
            }
        __syncthreads();
        #pragma unroll
        for (int p = 0; p < 4; ++p) {
            int idx = p * 256 + t;
            int r = idx >> 4, c = idx & 15;
            int node = base + r;
            if (node < N)
                *(half8*)(nodeEmb + (size_t)node * HID + c * 8) =
                    *(const half8*)&sOut[r * LDO + c * 8];
        }
        __syncthreads();
    }
}

// ---------------------------------------------------------------------------
// Kernel 2: per-edge MLP. 256 threads (4 waves x 32 cols), 64 edges/tile,
// async DMA gathers into XOR-swizzled sA, deferred MFMA layer-3.
// sH1/sH2 aliased into one 16 KB sH. Occupancy is limited by the UNIFIED
// VGPR+AGPR file (512/SIMD): 3 waves/SIMD needs total <= 170/wave. To fit:
//  - w3f fragments       -> sW3 LDS table (1 KB), read per tile at layer 3
//  - w1c/b1f/b2f scalars -> sB1/sB2/sWc LDS tables (1.5 KB), read at use
//  - nid[] prefetch moved AFTER layer-1 MFMA loop (peak-pressure region)
// Peak demand ~160 regs; launch_bounds(256,3) caps at 168 -> no spill,
// 3 blocks/CU. LDS ~52 KB -> 3x52=156 <= 160 KB. Verify: VGPR<=168 and
// WRITE_SIZE ~52 MB (if VGPR ~84 / WRITE ballooned, compiler spilled).
// ---------------------------------------------------------------------------
__global__ __launch_bounds__(256, 3) void edge_mlp_kernel(
    const _Float16* __restrict__ nodeEmb,
    const float* __restrict__ pos,
    const int* __restrict__ eidx,          // [2][E]
    const float* __restrict__ W1, const float* __restrict__ b1,   // [257][128]
    const float* __restrict__ W2, const float* __restrict__ b2,   // [128][128]
    const float* __restrict__ W3, const float* __restrict__ b3,   // [128][4]
    float* __restrict__ out, int E, int nTiles)
{
    __shared__ __align__(16) _Float16 sA[2 * TILE_M * HID];   // 32 KB, XOR swizzle
    __shared__ __align__(16) _Float16 sH[TILE_M * HID];       // 16 KB, XOR swizzle
                                                              // (h1 AND h2 staging)
    __shared__ float sDist[TILE_M];
    __shared__ __align__(16) _Float16 sW3[512];               // 1 KB  W3 frags
    __shared__ __align__(16) float sB1[HID];                  // b1
    __shared__ __align__(16) float sB2[HID];                  // b2
    __shared__ __align__(16) float sWc[HID];                  // W1 dist row

    const int t    = threadIdx.x;
    const int wave = t >> 6;
    const int lane = t & 63;
    const int quad = lane >> 4;
    const int l16  = lane & 15;
    const int colbase = wave * 32;        // each wave owns 32 output columns

    // ---- stage small constant tables into LDS (consumed after first B1) ----
    if (t < 64) {
        int kc = t >> 4, q = (t >> 2) & 3, c = t & 3;
        #pragma unroll
        for (int j = 0; j < 8; ++j)
            sW3[(kc * 16 + q * 4 + c) * 8 + j] =
                (_Float16)W3[(kc * 32 + q * 8 + j) * 4 + c];
    }
    if (t < HID) {
        sB1[t] = b1[t];
        sB2[t] = b2[t];
        sWc[t] = W1[256 * HID + t];
    }

    // ---- weight fragments (frag[j] = W[k0+quad*8+j][col]) ----
    half8 w1f[8][2];
    half8 w2f[4][2];
    #pragma unroll
    for (int ct = 0; ct < 2; ++ct) {
        int col = colbase + ct * 16 + l16;
        #pragma unroll
        for (int kc = 0; kc < 8; ++kc)
            #pragma unroll
            for (int j = 0; j < 8; ++j)
                w1f[kc][ct][j] = (_Float16)W1[(kc * 32 + quad * 8 + j) * HID + col];
        #pragma unroll
        for (int kc = 0; kc < 4; ++kc)
            #pragma unroll
            for (int j = 0; j < 8; ++j)
                w2f[kc][ct][j] = (_Float16)W2[(kc * 32 + quad * 8 + j) * HID + col];
    }
    const float b3v0 = b3[0], b3v1 = b3[1], b3v2 = b3[2], b3v3 = b3[3];

    int nid[8];
    float dpre = 0.f;

    auto load_nid = [&](int tl) {
        int eb = tl * TILE_M;
        #pragma unroll
        for (int i = 0; i < 8; ++i) {
            int cid = i * 256 + t;           // 0..2047 chunks of 16B
            int row = cid >> 4;              // 0..127: 0-63 src, 64-127 dst
            int r   = row & 63;
            int e   = eb + r; if (e >= E) e = E - 1;
            nid[i] = (row >> 6) ? eidx[(size_t)E + e] : eidx[e];
        }
    };
    auto load_dist = [&](int tl) -> float {
        if (t >= TILE_M) return 0.f;
        int e = tl * TILE_M + t; if (e >= E) e = E - 1;
        int s = eidx[e], d = eidx[(size_t)E + e];
        float dx = pos[3 * (size_t)s]     - pos[3 * (size_t)d];
        float dy = pos[3 * (size_t)s + 1] - pos[3 * (size_t)d + 1];
        float dz = pos[3 * (size_t)s + 2] - pos[3 * (size_t)d + 2];
        return sqrtf(dx * dx + dy * dy + dz * dz);
    };
    auto dma_issue = [&]() {
        #pragma unroll
        for (int i = 0; i < 8; ++i) {
            int cid = i * 256 + t;
            int row = cid >> 4;
            int cg  = (cid & 15) ^ (row & 15);      // XOR swizzle
            const _Float16* gp = nodeEmb + (size_t)nid[i] * HID + cg * 8;
            __builtin_amdgcn_global_load_lds(
                (__attribute__((address_space(1))) void*)gp,
                (__attribute__((address_space(3))) void*)&sA[(i * 256 + (t & 192)) * 8],
                16, 0, 0);
        }
    };

    bool havePrev = false;
    int prevEbase = 0;
    int tile = blockIdx.x;
    if (tile < nTiles) {
        load_nid(tile);
        dpre = load_dist(tile);
        dma_issue();                         // drains at first B1
    }

    for (; tile < nTiles; tile += gridDim.x) {
        const int ebase = tile * TILE_M;
        if (t < TILE_M) sDist[t] = dpre;
        __syncthreads();                     // B1: DMA(T) drained, sH=h2(T-1) ready

        // ---- layer 3 of previous tile: MFMA from sH (=h2), float4 store ----
        if (havePrev) {
            floatx4 acc3 = (floatx4){0.f, 0.f, 0.f, 0.f};
            #pragma unroll
            for (int kc = 0; kc < 4; ++kc) {
                int slot = ((kc * 4 + quad) ^ l16) * 8;
                half8 h  = *(const half8*)&sH[(wave * 16 + l16) * HID + slot];
                half8 w3 = *(const half8*)&sW3[(kc * 16 + quad * 4 + (l16 & 3)) * 8];
                acc3 = __builtin_amdgcn_mfma_f32_16x16x32_f16(w3, h, acc3, 0, 0, 0);
            }
            if (quad == 0) {
                int e = prevEbase + wave * 16 + l16;
                if (e < E) {
                    float4 o = {acc3[0] + b3v0, acc3[1] + b3v1,
                                acc3[2] + b3v2, acc3[3] + b3v3};
                    *(float4*)&out[(size_t)e * 4] = o;
                }
            }
        }
        // B1.5: all waves' L3 reads of sH(=h2(T-1)) done before epilogue-1
        // overwrites sH. lgkm-only: out-store + (not-yet-issued) DMA unaffected.
        barrier_lds_only();

        // ---- layer 1: bias (from LDS) in acc init, XOR-swizzled sA reads ----
        floatx4 acc[2][4];
        {
            floatx4 b1v0 = *(const floatx4*)&sB1[colbase + 0 * 16 + quad * 4];
            floatx4 b1v1 = *(const floatx4*)&sB1[colbase + 1 * 16 + quad * 4];
            #pragma unroll
            for (int rt = 0; rt < 4; ++rt) { acc[0][rt] = b1v0; acc[1][rt] = b1v1; }
        }
        #pragma unroll
        for (int kc = 0; kc < 8; ++kc) {
            int hf   = kc >> 2;
            int cg   = (kc & 3) * 4 + quad;
            int slot = (cg ^ l16) * 8;
            const _Float16* base = &sA[(hf * TILE_M + l16) * HID + slot];
            half8 a0 = *(const half8*)(base + 0 * 16 * HID);
            half8 a1 = *(const half8*)(base + 1 * 16 * HID);
            half8 a2 = *(const half8*)(base + 2 * 16 * HID);
            half8 a3 = *(const half8*)(base + 3 * 16 * HID);
            acc[0][0] = __builtin_amdgcn_mfma_f32_16x16x32_f16(w1f[kc][0], a0, acc[0][0], 0, 0, 0);
            acc[0][1] = __builtin_amdgcn_mfma_f32_16x16x32_f16(w1f[kc][0], a1, acc[0][1], 0, 0, 0);
            acc[0][2] = __builtin_amdgcn_mfma_f32_16x16x32_f16(w1f[kc][0], a2, acc[0][2], 0, 0, 0);
            acc[0][3] = __builtin_amdgcn_mfma_f32_16x16x32_f16(w1f[kc][0], a3, acc[0][3], 0, 0, 0);
            acc[1][0] = __builtin_amdgcn_mfma_f32_16x16x32_f16(w1f[kc][1], a0, acc[1][0], 0, 0, 0);
            acc[1][1] = __builtin_amdgcn_mfma_f32_16x16x32_f16(w1f[kc][1], a1, acc[1][1], 0, 0, 0);
            acc[1][2] = __builtin_amdgcn_mfma_f32_16x16x32_f16(w1f[kc][1], a2, acc[1][2], 0, 0, 0);
            acc[1][3] = __builtin_amdgcn_mfma_f32_16x16x32_f16(w1f[kc][1], a3, acc[1][3], 0, 0, 0);
        }

        // ---- prefetch next tile metadata AFTER the peak-pressure region;
        //      epilogue-1's VALU covers the load latency before dma_issue ----
        int nxt = tile + gridDim.x;
        if (nxt < nTiles) {
            load_nid(nxt);
            dpre = load_dist(nxt);
        }

        // epilogue 1 -> sH (XOR-swizzled uint2 writes); w1c from LDS
        {
            floatx4 w1cv[2];
            w1cv[0] = *(const floatx4*)&sWc[colbase + 0 * 16 + quad * 4];
            w1cv[1] = *(const floatx4*)&sWc[colbase + 1 * 16 + quad * 4];
            #pragma unroll
            for (int rt = 0; rt < 4; ++rt) {
                int m = rt * 16 + l16;
                float d = sDist[m];
                #pragma unroll
                for (int ct = 0; ct < 2; ++ct) {
                    float v0 = fast_silu(fmaf(d, w1cv[ct][0], acc[ct][rt][0]));
                    float v1 = fast_silu(fmaf(d, w1cv[ct][1], acc[ct][rt][1]));
                    float v2 = fast_silu(fmaf(d, w1cv[ct][2], acc[ct][rt][2]));
                    float v3 = fast_silu(fmaf(d, w1cv[ct][3], acc[ct][rt][3]));
                    uint2 w;
                    w.x = pk2(v0, v1);
                    w.y = pk2(v2, v3);
                    int cgb  = wave * 4 + ct * 2 + (quad >> 1);
                    int slot = cgb ^ l16;
                    *(uint2*)&sH[m * HID + slot * 8 + (quad & 1) * 4] = w;
                }
            }
        }
        barrier_lds_only();                  // B2: LDS-only; prefetch loads live

        // ---- async DMA for next tile (sA free; overlaps L2+L3+next B1) ----
        if (nxt < nTiles) dma_issue();

        // ---- layer 2: bias (from LDS) in acc init ----
        floatx4 acc2[2][4];
        {
            floatx4 b2v0 = *(const floatx4*)&sB2[colbase + 0 * 16 + quad * 4];
            floatx4 b2v1 = *(const floatx4*)&sB2[colbase + 1 * 16 + quad * 4];
            #pragma unroll
            for (int rt = 0; rt < 4; ++rt) { acc2[0][rt] = b2v0; acc2[1][rt] = b2v1; }
        }
        #pragma unroll
        for (int kc = 0; kc < 4; ++kc) {
            int slot = ((kc * 4 + quad) ^ l16) * 8;
            half8 a0 = *(const half8*)&sH[(0 * 16 + l16) * HID + slot];
            half8 a1 = *(const half8*)&sH[(1 * 16 + l16) * HID + slot];
            half8 a2 = *(const half8*)&sH[(2 * 16 + l16) * HID + slot];
            half8 a3 = *(const half8*)&sH[(3 * 16 + l16) * HID + slot];
            acc2[0][0] = __builtin_amdgcn_mfma_f32_16x16x32_f16(w2f[kc][0], a0, acc2[0][0], 0, 0, 0);
            acc2[0][1] = __builtin_amdgcn_mfma_f32_16x16x32_f16(w2f[kc][0], a1, acc2[0][1], 0, 0, 0);
            acc2[0][2] = __builtin_amdgcn_mfma_f32_16x16x32_f16(w2f[kc][0], a2, acc2[0][2], 0, 0, 0);
            acc2[0][3] = __builtin_amdgcn_mfma_f32_16x16x32_f16(w2f[kc][0], a3, acc2[0][3], 0, 0, 0);
            acc2[1][0] = __builtin_amdgcn_mfma_f32_16x16x32_f16(w2f[kc][1], a0, acc2[1][0], 0, 0, 0);
            acc2[1][1] = __builtin_amdgcn_mfma_f32_16x16x32_f16(w2f[kc][1], a1, acc2[1][1], 0, 0, 0);
            acc2[1][2] = __builtin_amdgcn_mfma_f32_16x16x32_f16(w2f[kc][1], a2, acc2[1][2], 0, 0, 0);
            acc2[1][3] = __builtin_amdgcn_mfma_f32_16x16x32_f16(w2f[kc][1], a3, acc2[1][3], 0, 0, 0);
        }
        // B2.5: all waves' layer-2 reads of sH(=h1) done before epilogue-2
        // overwrites sH with h2. lgkm-only: DMA stays in flight.
        barrier_lds_only();

        // epilogue 2 -> sH (h2 staging for deferred layer 3)
        #pragma unroll
        for (int rt = 0; rt < 4; ++rt) {
            int m = rt * 16 + l16;
            #pragma unroll
            for (int ct = 0; ct < 2; ++ct) {
                float v0 = fast_silu(acc2[ct][rt][0]);
                float v1 = fast_silu(acc2[ct][rt][1]);
                float v2 = fast_silu(acc2[ct][rt][2]);
                float v3 = fast_silu(acc2[ct][rt][3]);
                uint2 w;
                w.x = pk2(v0, v1);
                w.y = pk2(v2, v3);
                int cgb  = wave * 4 + ct * 2 + (quad >> 1);
                int slot = cgb ^ l16;
                *(uint2*)&sH[m * HID + slot * 8 + (quad & 1) * 4] = w;
            }
        }
        havePrev = true;
        prevEbase = ebase;
    }

    // ---- flush: layer 3 of the final tile ----
    if (havePrev) {
        __syncthreads();
        floatx4 acc3 = (floatx4){0.f, 0.f, 0.f, 0.f};
        #pragma unroll
        for (int kc = 0; kc < 4; ++kc) {
            int slot = ((kc * 4 + quad) ^ l16) * 8;
            half8 h  = *(const half8*)&sH[(wave * 16 + l16) * HID + slot];
            half8 w3 = *(const half8*)&sW3[(kc * 16 + quad * 4 + (l16 & 3)) * 8];
            acc3 = __builtin_amdgcn_mfma_f32_16x16x32_f16(w3, h, acc3, 0, 0, 0);
        }
        if (quad == 0) {
            int e = prevEbase + wave * 16 + l16;
            if (e < E) {
                float4 o = {acc3[0] + b3v0, acc3[1] + b3v1,
                            acc3[2] + b3v2, acc3[3] + b3v3};
                *(float4*)&out[(size_t)e * 4] = o;
            }
        }
    }
}

extern "C" void kernel_launch(void* const* d_in, const int* in_sizes, int n_in,
                              void* d_out, int out_size, void* d_ws, size_t ws_size,
                              hipStream_t stream) {
    const float* x   = (const float*)d_in[0];
    const float* pos = (const float*)d_in[1];
    const int*  eidx = (const int*)d_in[2];
    const float* Wa = (const float*)d_in[3];
    const float* ba = (const float*)d_in[4];
    const float* Wp = (const float*)d_in[5];
    const float* bp = (const float*)d_in[6];
    const float* W1 = (const float*)d_in[7];
    const float* b1 = (const float*)d_in[8];
    const float* W2 = (const float*)d_in[9];
    const float* b2 = (const float*)d_in[10];
    const float* W3 = (const float*)d_in[11];
    const float* b3 = (const float*)d_in[12];
    float* out = (float*)d_out;

    int N = in_sizes[0] / 16;   // ATOM_DIM
    int E = in_sizes[2] / 2;

    _Float16* nodeEmb = (_Float16*)d_ws;   // N*128 fp16 = 25.6 MB

    int nodeTiles = (N + 63) / 64;
    node_emb_kernel<<<nodeTiles, 256, 0, stream>>>(x, pos, Wa, ba, Wp, bp, nodeEmb, N);

    int nTiles = (E + TILE_M - 1) / TILE_M;
    // 3 blocks/CU x 256 CUs
    edge_mlp_kernel<<<768, 256, 0, stream>>>(nodeEmb, pos, eidx,
                                             W1, b1, W2, b2, W3, b3,
                                             out, E, nTiles);
}

// Round 4
// 419.806 us; speedup vs baseline: 1.3990x; 1.3990x over previous
//
#include <hip/hip_runtime.h>
#include <hip/hip_bf16.h>
#include <hip/hip_fp16.h>

typedef _Float16 half8 __attribute__((ext_vector_type(8)));
typedef _Float16 half4 __attribute__((ext_vector_type(4)));
typedef __fp16 fp16x2 __attribute__((ext_vector_type(2)));
typedef float floatx4 __attribute__((ext_vector_type(4)));

#define HID 128
#define TILE_M 64

__device__ __forceinline__ float fast_silu(float v) {
    float e = __expf(-v);
    return v * __builtin_amdgcn_rcpf(1.f + e);
}

__device__ __forceinline__ unsigned int pk2(float a, float b) {
    fp16x2 h = __builtin_amdgcn_cvt_pkrtz(a, b);
    return __builtin_bit_cast(unsigned int, h);
}

// LDS-only barrier: drains LDS ops but leaves global (vmcnt) traffic in
// flight. Use ONLY where the barrier guards LDS-LDS hazards exclusively.
__device__ __forceinline__ void barrier_lds_only() {
    asm volatile("s_waitcnt lgkmcnt(0)\n\ts_barrier" ::: "memory");
}

// ---------------------------------------------------------------------------
// Kernel 0: pack W1 (fp32 [257][128], rows 0..255) into fp16 fragment layout
// P[kc][c][q][j] = W1[(kc*32+q*8+j)][c], so a wave's (kc,ct) fragment load is
// one fully-coalesced 1 KB global_load_dwordx4 across 64 lanes. 64 KB total:
// permanently L2-resident during the edge kernel.
// ---------------------------------------------------------------------------
__global__ __launch_bounds__(256) void prep_w1_kernel(
    const float* __restrict__ W1, _Float16* __restrict__ P)
{
    int idx = blockIdx.x * 256 + threadIdx.x;   // (kc,c,q): 8*128*4 = 4096
    if (idx >= 4096) return;
    int q = idx & 3, c = (idx >> 2) & 127, kc = idx >> 9;
    #pragma unroll
    for (int j = 0; j < 8; ++j)
        P[(size_t)idx * 8 + j] = (_Float16)W1[(kc * 32 + q * 8 + j) * HID + c];
}

// ---------------------------------------------------------------------------
// Kernel 1: node_emb = [x|pos|0-pad] @ [Wa;Wp;0] + (ba+bp). Block handles a
// 64-node tile via MFMA; output assembled in padded LDS, stored coalesced.
// ---------------------------------------------------------------------------
#define LDO 136
__global__ __launch_bounds__(256) void node_emb_kernel(
    const float* __restrict__ x, const float* __restrict__ pos,
    const float* __restrict__ Wa, const float* __restrict__ ba,
    const float* __restrict__ Wp, const float* __restrict__ bp,
    _Float16* __restrict__ nodeEmb, int N)
{
    __shared__ __align__(16) _Float16 sOut[64 * LDO];   // 17 KB
    const int t    = threadIdx.x;
    const int wave = t >> 6;
    const int lane = t & 63;
    const int quad = lane >> 4;
    const int l16  = lane & 15;

    half8 wf[2];
    floatx4 bias[2];
    #pragma unroll
    for (int ct = 0; ct < 2; ++ct) {
        int col = wave * 32 + ct * 16 + l16;
        #pragma unroll
        for (int j = 0; j < 8; ++j) {
            int k = quad * 8 + j;
            float w = 0.f;
            if (k < 16) w = Wa[k * HID + col];
            else if (k < 19) w = Wp[(k - 16) * HID + col];
            wf[ct][j] = (_Float16)w;
        }
        #pragma unroll
        for (int i = 0; i < 4; ++i) {
            int c2 = wave * 32 + ct * 16 + quad * 4 + i;
            bias[ct][i] = ba[c2] + bp[c2];
        }
    }

    int nTiles = (N + 63) >> 6;
    for (int tile = blockIdx.x; tile < nTiles; tile += gridDim.x) {
        int base = tile * 64;
        half8 af[4];
        #pragma unroll
        for (int rt = 0; rt < 4; ++rt) {
            int node = base + rt * 16 + l16;
            int nd = node < N ? node : N - 1;
            half8 a = (half8){0, 0, 0, 0, 0, 0, 0, 0};
            if (quad < 2) {
                const float* xp = x + (size_t)nd * 16 + quad * 8;
                float4 v0 = *(const float4*)xp;
                float4 v1 = *(const float4*)(xp + 4);
                a[0] = (_Float16)v0.x; a[1] = (_Float16)v0.y;
                a[2] = (_Float16)v0.z; a[3] = (_Float16)v0.w;
                a[4] = (_Float16)v1.x; a[5] = (_Float16)v1.y;
                a[6] = (_Float16)v1.z; a[7] = (_Float16)v1.w;
            } else if (quad == 2) {
                const float* pp = pos + (size_t)nd * 3;
                a[0] = (_Float16)pp[0]; a[1] = (_Float16)pp[1]; a[2] = (_Float16)pp[2];
            }
            af[rt] = a;
        }
        #pragma unroll
        for (int ct = 0; ct < 2; ++ct)
            #pragma unroll
            for (int rt = 0; rt < 4; ++rt) {
                floatx4 d = bias[ct];
                d = __builtin_amdgcn_mfma_f32_16x16x32_f16(wf[ct], af[rt], d, 0, 0, 0);
                half4 hv;
                hv[0] = (_Float16)d[0]; hv[1] = (_Float16)d[1];
                hv[2] = (_Float16)d[2]; hv[3] = (_Float16)d[3];
                *(half4*)&sOut[(rt * 16 + l16) * LDO + wave * 32 + ct * 16 + quad * 4] = hv;
            }
        __syncthreads();
        #pragma unroll
        for (int p = 0; p < 4; ++p) {
            int idx = p * 256 + t;
            int r = idx >> 4, c = idx & 15;
            int node = base + r;
            if (node < N)
                *(half8*)(nodeEmb + (size_t)node * HID + c * 8) =
                    *(const half8*)&sOut[r * LDO + c * 8];
        }
        __syncthreads();
    }
}

// ---------------------------------------------------------------------------
// Kernel 2: per-edge MLP. 256 threads (4 waves x 32 cols), 64 edges/tile,
// async DMA gathers into XOR-swizzled sA, deferred MFMA layer-3, aliased sH.
// Occupancy target: 3 waves/SIMD => total regs <= ~170/wave. Register diet:
//  - w1f (64 VGPR)       -> STREAMED from L2-resident packed W1 (w1p),
//                           double-buffered 1 kc ahead (16 VGPR)
//  - w3f fragments       -> sW3 LDS table (1 KB)
//  - w1c/b1f/b2f scalars -> sB1/sB2/sWc LDS tables
// Peak demand ~134 regs (w2f 32 + wbuf 16 + acc 32 + afrags 16 + nid 8 +
// temps ~30) -> fits the (256,3) cap of 168 WITH margin (r1/r3 spilled at
// demand ~190). Verify: VGPR_Count > 84 and WRITE_SIZE ~52 MB = no spill.
// LDS 52.2 KB -> 3x52.2 = 156.7 <= 160 KB -> 3 blocks/CU.
// ---------------------------------------------------------------------------
__global__ __launch_bounds__(256, 3) void edge_mlp_kernel(
    const _Float16* __restrict__ nodeEmb,
    const _Float16* __restrict__ w1p,      // packed W1 frags [8][128][4][8]
    const float* __restrict__ pos,
    const int* __restrict__ eidx,          // [2][E]
    const float* __restrict__ W1, const float* __restrict__ b1,   // [257][128]
    const float* __restrict__ W2, const float* __restrict__ b2,   // [128][128]
    const float* __restrict__ W3, const float* __restrict__ b3,   // [128][4]
    float* __restrict__ out, int E, int nTiles)
{
    __shared__ __align__(16) _Float16 sA[2 * TILE_M * HID];   // 32 KB, XOR swizzle
    __shared__ __align__(16) _Float16 sH[TILE_M * HID];       // 16 KB, XOR swizzle
                                                              // (h1 AND h2 staging)
    __shared__ float sDist[TILE_M];
    __shared__ __align__(16) _Float16 sW3[512];               // 1 KB  W3 frags
    __shared__ __align__(16) float sB1[HID];                  // b1
    __shared__ __align__(16) float sB2[HID];                  // b2
    __shared__ __align__(16) float sWc[HID];                  // W1 dist row

    const int t    = threadIdx.x;
    const int wave = t >> 6;
    const int lane = t & 63;
    const int quad = lane >> 4;
    const int l16  = lane & 15;
    const int colbase = wave * 32;        // each wave owns 32 output columns

    // ---- stage small constant tables into LDS (consumed after first B1) ----
    if (t < 64) {
        int kc = t >> 4, q = (t >> 2) & 3, c = t & 3;
        #pragma unroll
        for (int j = 0; j < 8; ++j)
            sW3[(kc * 16 + q * 4 + c) * 8 + j] =
                (_Float16)W3[(kc * 32 + q * 8 + j) * 4 + c];
    }
    if (t < HID) {
        sB1[t] = b1[t];
        sB2[t] = b2[t];
        sWc[t] = W1[256 * HID + t];
    }

    // ---- persistent weight fragments: W2 only (32 VGPR) ----
    half8 w2f[4][2];
    #pragma unroll
    for (int ct = 0; ct < 2; ++ct) {
        int col = colbase + ct * 16 + l16;
        #pragma unroll
        for (int kc = 0; kc < 4; ++kc)
            #pragma unroll
            for (int j = 0; j < 8; ++j)
                w2f[kc][ct][j] = (_Float16)W2[(kc * 32 + quad * 8 + j) * HID + col];
    }
    const float b3v0 = b3[0], b3v1 = b3[1], b3v2 = b3[2], b3v3 = b3[3];

    // streamed-W1 fragment address: one coalesced 1 KB load per (kc,ct) per wave
    auto w1addr = [&](int kc, int ct) {
        return (const half8*)(w1p +
            ((size_t)(kc * 128 + colbase + ct * 16 + l16) * 4 + quad) * 8);
    };

    int nid[8];
    float dpre = 0.f;

    auto load_nid = [&](int tl) {
        int eb = tl * TILE_M;
        #pragma unroll
        for (int i = 0; i < 8; ++i) {
            int cid = i * 256 + t;           // 0..2047 chunks of 16B
            int row = cid >> 4;              // 0..127: 0-63 src, 64-127 dst
            int r   = row & 63;
            int e   = eb + r; if (e >= E) e = E - 1;
            nid[i] = (row >> 6) ? eidx[(size_t)E + e] : eidx[e];
        }
    };
    auto load_dist = [&](int tl) -> float {
        if (t >= TILE_M) return 0.f;
        int e = tl * TILE_M + t; if (e >= E) e = E - 1;
        int s = eidx[e], d = eidx[(size_t)E + e];
        float dx = pos[3 * (size_t)s]     - pos[3 * (size_t)d];
        float dy = pos[3 * (size_t)s + 1] - pos[3 * (size_t)d + 1];
        float dz = pos[3 * (size_t)s + 2] - pos[3 * (size_t)d + 2];
        return sqrtf(dx * dx + dy * dy + dz * dz);
    };
    auto dma_issue = [&]() {
        #pragma unroll
        for (int i = 0; i < 8; ++i) {
            int cid = i * 256 + t;
            int row = cid >> 4;
            int cg  = (cid & 15) ^ (row & 15);      // XOR swizzle
            const _Float16* gp = nodeEmb + (size_t)nid[i] * HID + cg * 8;
            __builtin_amdgcn_global_load_lds(
                (__attribute__((address_space(1))) void*)gp,
                (__attribute__((address_space(3))) void*)&sA[(i * 256 + (t & 192)) * 8],
                16, 0, 0);
        }
    };

    bool havePrev = false;
    int prevEbase = 0;
    int tile = blockIdx.x;
    if (tile < nTiles) {
        load_nid(tile);
        dpre = load_dist(tile);
        dma_issue();                         // drains at first B1
    }

    for (; tile < nTiles; tile += gridDim.x) {
        const int ebase = tile * TILE_M;
        if (t < TILE_M) sDist[t] = dpre;
        __syncthreads();                     // B1: DMA(T) drained, sH=h2(T-1) ready

        // ---- layer 3 of previous tile: MFMA from sH (=h2), float4 store ----
        if (havePrev) {
            floatx4 acc3 = (floatx4){0.f, 0.f, 0.f, 0.f};
            #pragma unroll
            for (int kc = 0; kc < 4; ++kc) {
                int slot = ((kc * 4 + quad) ^ l16) * 8;
                half8 h  = *(const half8*)&sH[(wave * 16 + l16) * HID + slot];
                half8 w3 = *(const half8*)&sW3[(kc * 16 + quad * 4 + (l16 & 3)) * 8];
                acc3 = __builtin_amdgcn_mfma_f32_16x16x32_f16(w3, h, acc3, 0, 0, 0);
            }
            if (quad == 0) {
                int e = prevEbase + wave * 16 + l16;
                if (e < E) {
                    float4 o = {acc3[0] + b3v0, acc3[1] + b3v1,
                                acc3[2] + b3v2, acc3[3] + b3v3};
                    *(float4*)&out[(size_t)e * 4] = o;
                }
            }
        }
        // B1.5: all waves' L3 reads of sH(=h2(T-1)) done before epilogue-1
        // overwrites sH. lgkm-only: out-store + (not-yet-issued) DMA unaffected.
        barrier_lds_only();

        // ---- layer 1: bias (from LDS) in acc init, XOR-swizzled sA reads,
        //      W1 fragments streamed from L2 (double-buffered 1 kc ahead) ----
        floatx4 acc[2][4];
        {
            floatx4 b1v0 = *(const floatx4*)&sB1[colbase + 0 * 16 + quad * 4];
            floatx4 b1v1 = *(const floatx4*)&sB1[colbase + 1 * 16 + quad * 4];
            #pragma unroll
            for (int rt = 0; rt < 4; ++rt) { acc[0][rt] = b1v0; acc[1][rt] = b1v1; }
        }
        {
            half8 wcA0 = *w1addr(0, 0), wcA1 = *w1addr(0, 1);
            half8 wcB0, wcB1;
            #pragma unroll
            for (int kp = 0; kp < 4; ++kp) {
                const int kcE = kp * 2;          // even kc -> uses wcA
                const int kcO = kcE + 1;         // odd  kc -> uses wcB
                wcB0 = *w1addr(kcO, 0); wcB1 = *w1addr(kcO, 1);
                {
                    int hf   = kcE >> 2;
                    int cg   = (kcE & 3) * 4 + quad;
                    int slot = (cg ^ l16) * 8;
                    const _Float16* base = &sA[(hf * TILE_M + l16) * HID + slot];
                    half8 a0 = *(const half8*)(base + 0 * 16 * HID);
                    half8 a1 = *(const half8*)(base + 1 * 16 * HID);
                    half8 a2 = *(const half8*)(base + 2 * 16 * HID);
                    half8 a3 = *(const half8*)(base + 3 * 16 * HID);
                    acc[0][0] = __builtin_amdgcn_mfma_f32_16x16x32_f16(wcA0, a0, acc[0][0], 0, 0, 0);
                    acc[0][1] = __builtin_amdgcn_mfma_f32_16x16x32_f16(wcA0, a1, acc[0][1], 0, 0, 0);
                    acc[0][2] = __builtin_amdgcn_mfma_f32_16x16x32_f16(wcA0, a2, acc[0][2], 0, 0, 0);
                    acc[0][3] = __builtin_amdgcn_mfma_f32_16x16x32_f16(wcA0, a3, acc[0][3], 0, 0, 0);
                    acc[1][0] = __builtin_amdgcn_mfma_f32_16x16x32_f16(wcA1, a0, acc[1][0], 0, 0, 0);
                    acc[1][1] = __builtin_amdgcn_mfma_f32_16x16x32_f16(wcA1, a1, acc[1][1], 0, 0, 0);
                    acc[1][2] = __builtin_amdgcn_mfma_f32_16x16x32_f16(wcA1, a2, acc[1][2], 0, 0, 0);
                    acc[1][3] = __builtin_amdgcn_mfma_f32_16x16x32_f16(wcA1, a3, acc[1][3], 0, 0, 0);
                }
                if (kp < 3) { wcA0 = *w1addr(kcE + 2, 0); wcA1 = *w1addr(kcE + 2, 1); }
                {
                    int hf   = kcO >> 2;
                    int cg   = (kcO & 3) * 4 + quad;
                    int slot = (cg ^ l16) * 8;
                    const _Float16* base = &sA[(hf * TILE_M + l16) * HID + slot];
                    half8 a0 = *(const half8*)(base + 0 * 16 * HID);
                    half8 a1 = *(const half8*)(base + 1 * 16 * HID);
                    half8 a2 = *(const half8*)(base + 2 * 16 * HID);
                    half8 a3 = *(const half8*)(base + 3 * 16 * HID);
                    acc[0][0] = __builtin_amdgcn_mfma_f32_16x16x32_f16(wcB0, a0, acc[0][0], 0, 0, 0);
                    acc[0][1] = __builtin_amdgcn_mfma_f32_16x16x32_f16(wcB0, a1, acc[0][1], 0, 0, 0);
                    acc[0][2] = __builtin_amdgcn_mfma_f32_16x16x32_f16(wcB0, a2, acc[0][2], 0, 0, 0);
                    acc[0][3] = __builtin_amdgcn_mfma_f32_16x16x32_f16(wcB0, a3, acc[0][3], 0, 0, 0);
                    acc[1][0] = __builtin_amdgcn_mfma_f32_16x16x32_f16(wcB1, a0, acc[1][0], 0, 0, 0);
                    acc[1][1] = __builtin_amdgcn_mfma_f32_16x16x32_f16(wcB1, a1, acc[1][1], 0, 0, 0);
                    acc[1][2] = __builtin_amdgcn_mfma_f32_16x16x32_f16(wcB1, a2, acc[1][2], 0, 0, 0);
                    acc[1][3] = __builtin_amdgcn_mfma_f32_16x16x32_f16(wcB1, a3, acc[1][3], 0, 0, 0);
                }
            }
        }

        // ---- prefetch next tile metadata AFTER the peak-pressure region;
        //      epilogue-1's VALU covers the load latency before dma_issue ----
        int nxt = tile + gridDim.x;
        if (nxt < nTiles) {
            load_nid(nxt);
            dpre = load_dist(nxt);
        }

        // epilogue 1 -> sH (XOR-swizzled uint2 writes); w1c from LDS
        {
            floatx4 w1cv[2];
            w1cv[0] = *(const floatx4*)&sWc[colbase + 0 * 16 + quad * 4];
            w1cv[1] = *(const floatx4*)&sWc[colbase + 1 * 16 + quad * 4];
            #pragma unroll
            for (int rt = 0; rt < 4; ++rt) {
                int m = rt * 16 + l16;
                float d = sDist[m];
                #pragma unroll
                for (int ct = 0; ct < 2; ++ct) {
                    float v0 = fast_silu(fmaf(d, w1cv[ct][0], acc[ct][rt][0]));
                    float v1 = fast_silu(fmaf(d, w1cv[ct][1], acc[ct][rt][1]));
                    float v2 = fast_silu(fmaf(d, w1cv[ct][2], acc[ct][rt][2]));
                    float v3 = fast_silu(fmaf(d, w1cv[ct][3], acc[ct][rt][3]));
                    uint2 w;
                    w.x = pk2(v0, v1);
                    w.y = pk2(v2, v3);
                    int cgb  = wave * 4 + ct * 2 + (quad >> 1);
                    int slot = cgb ^ l16;
                    *(uint2*)&sH[m * HID + slot * 8 + (quad & 1) * 4] = w;
                }
            }
        }
        barrier_lds_only();                  // B2: LDS-only; prefetch loads live

        // ---- async DMA for next tile (sA free; overlaps L2+L3+next B1) ----
        if (nxt < nTiles) dma_issue();

        // ---- layer 2: bias (from LDS) in acc init ----
        floatx4 acc2[2][4];
        {
            floatx4 b2v0 = *(const floatx4*)&sB2[colbase + 0 * 16 + quad * 4];
            floatx4 b2v1 = *(const floatx4*)&sB2[colbase + 1 * 16 + quad * 4];
            #pragma unroll
            for (int rt = 0; rt < 4; ++rt) { acc2[0][rt] = b2v0; acc2[1][rt] = b2v1; }
        }
        #pragma unroll
        for (int kc = 0; kc < 4; ++kc) {
            int slot = ((kc * 4 + quad) ^ l16) * 8;
            half8 a0 = *(const half8*)&sH[(0 * 16 + l16) * HID + slot];
            half8 a1 = *(const half8*)&sH[(1 * 16 + l16) * HID + slot];
            half8 a2 = *(const half8*)&sH[(2 * 16 + l16) * HID + slot];
            half8 a3 = *(const half8*)&sH[(3 * 16 + l16) * HID + slot];
            acc2[0][0] = __builtin_amdgcn_mfma_f32_16x16x32_f16(w2f[kc][0], a0, acc2[0][0], 0, 0, 0);
            acc2[0][1] = __builtin_amdgcn_mfma_f32_16x16x32_f16(w2f[kc][0], a1, acc2[0][1], 0, 0, 0);
            acc2[0][2] = __builtin_amdgcn_mfma_f32_16x16x32_f16(w2f[kc][0], a2, acc2[0][2], 0, 0, 0);
            acc2[0][3] = __builtin_amdgcn_mfma_f32_16x16x32_f16(w2f[kc][0], a3, acc2[0][3], 0, 0, 0);
            acc2[1][0] = __builtin_amdgcn_mfma_f32_16x16x32_f16(w2f[kc][1], a0, acc2[1][0], 0, 0, 0);
            acc2[1][1] = __builtin_amdgcn_mfma_f32_16x16x32_f16(w2f[kc][1], a1, acc2[1][1], 0, 0, 0);
            acc2[1][2] = __builtin_amdgcn_mfma_f32_16x16x32_f16(w2f[kc][1], a2, acc2[1][2], 0, 0, 0);
            acc2[1][3] = __builtin_amdgcn_mfma_f32_16x16x32_f16(w2f[kc][1], a3, acc2[1][3], 0, 0, 0);
        }
        // B2.5: all waves' layer-2 reads of sH(=h1) done before epilogue-2
        // overwrites sH with h2. lgkm-only: DMA stays in flight.
        barrier_lds_only();

        // epilogue 2 -> sH (h2 staging for deferred layer 3)
        #pragma unroll
        for (int rt = 0; rt < 4; ++rt) {
            int m = rt * 16 + l16;
            #pragma unroll
            for (int ct = 0; ct < 2; ++ct) {
                float v0 = fast_silu(acc2[ct][rt][0]);
                float v1 = fast_silu(acc2[ct][rt][1]);
                float v2 = fast_silu(acc2[ct][rt][2]);
                float v3 = fast_silu(acc2[ct][rt][3]);
                uint2 w;
                w.x = pk2(v0, v1);
                w.y = pk2(v2, v3);
                int cgb  = wave * 4 + ct * 2 + (quad >> 1);
                int slot = cgb ^ l16;
                *(uint2*)&sH[m * HID + slot * 8 + (quad & 1) * 4] = w;
            }
        }
        havePrev = true;
        prevEbase = ebase;
    }

    // ---- flush: layer 3 of the final tile ----
    if (havePrev) {
        __syncthreads();
        floatx4 acc3 = (floatx4){0.f, 0.f, 0.f, 0.f};
        #pragma unroll
        for (int kc = 0; kc < 4; ++kc) {
            int slot = ((kc * 4 + quad) ^ l16) * 8;
            half8 h  = *(const half8*)&sH[(wave * 16 + l16) * HID + slot];
            half8 w3 = *(const half8*)&sW3[(kc * 16 + quad * 4 + (l16 & 3)) * 8];
            acc3 = __builtin_amdgcn_mfma_f32_16x16x32_f16(w3, h, acc3, 0, 0, 0);
        }
        if (quad == 0) {
            int e = prevEbase + wave * 16 + l16;
            if (e < E) {
                float4 o = {acc3[0] + b3v0, acc3[1] + b3v1,
                            acc3[2] + b3v2, acc3[3] + b3v3};
                *(float4*)&out[(size_t)e * 4] = o;
            }
        }
    }
}

extern "C" void kernel_launch(void* const* d_in, const int* in_sizes, int n_in,
                              void* d_out, int out_size, void* d_ws, size_t ws_size,
                              hipStream_t stream) {
    const float* x   = (const float*)d_in[0];
    const float* pos = (const float*)d_in[1];
    const int*  eidx = (const int*)d_in[2];
    const float* Wa = (const float*)d_in[3];
    const float* ba = (const float*)d_in[4];
    const float* Wp = (const float*)d_in[5];
    const float* bp = (const float*)d_in[6];
    const float* W1 = (const float*)d_in[7];
    const float* b1 = (const float*)d_in[8];
    const float* W2 = (const float*)d_in[9];
    const float* b2 = (const float*)d_in[10];
    const float* W3 = (const float*)d_in[11];
    const float* b3 = (const float*)d_in[12];
    float* out = (float*)d_out;

    int N = in_sizes[0] / 16;   // ATOM_DIM
    int E = in_sizes[2] / 2;

    _Float16* nodeEmb = (_Float16*)d_ws;                 // N*128 fp16 = 25.6 MB
    _Float16* w1p = (_Float16*)((char*)d_ws + (size_t)N * HID * 2);  // +64 KB

    prep_w1_kernel<<<16, 256, 0, stream>>>(W1, w1p);

    int nodeTiles = (N + 63) / 64;
    node_emb_kernel<<<nodeTiles, 256, 0, stream>>>(x, pos, Wa, ba, Wp, bp, nodeEmb, N);

    int nTiles = (E + TILE_M - 1) / TILE_M;
    // 3 blocks/CU x 256 CUs
    edge_mlp_kernel<<<768, 256, 0, stream>>>(nodeEmb, w1p, pos, eidx,
                                             W1, b1, W2, b2, W3, b3,
                                             out, E, nTiles);
}

// Round 5
// 355.494 us; speedup vs baseline: 1.6521x; 1.1809x over previous
//
#include <hip/hip_runtime.h>
#include <hip/hip_bf16.h>
#include <hip/hip_fp16.h>

typedef _Float16 half8 __attribute__((ext_vector_type(8)));
typedef _Float16 half4 __attribute__((ext_vector_type(4)));
typedef __fp16 fp16x2 __attribute__((ext_vector_type(2)));
typedef float floatx4 __attribute__((ext_vector_type(4)));

#define HID 128
#define TILE_M 64
#define TSZ (2 * TILE_M * HID)    // one tile's A-data: 16384 halfs = 32 KB
#define H2OFF (TILE_M * HID)      // h2 lives in the 2nd half of the buffer

__device__ __forceinline__ float fast_silu(float v) {
    float e = __expf(-v);
    return v * __builtin_amdgcn_rcpf(1.f + e);
}

__device__ __forceinline__ unsigned int pk2(float a, float b) {
    fp16x2 h = __builtin_amdgcn_cvt_pkrtz(a, b);
    return __builtin_bit_cast(unsigned int, h);
}

// LDS-only barrier: drains LDS ops but leaves global (vmcnt) traffic in
// flight. Use ONLY where the barrier guards LDS-LDS hazards exclusively.
__device__ __forceinline__ void barrier_lds_only() {
    asm volatile("s_waitcnt lgkmcnt(0)\n\ts_barrier" ::: "memory");
}

// ---------------------------------------------------------------------------
// Kernel 1: node_emb = [x|pos|0-pad] @ [Wa;Wp;0] + (ba+bp). Block handles a
// 64-node tile via MFMA; output assembled in padded LDS, stored coalesced.
// ---------------------------------------------------------------------------
#define LDO 136
__global__ __launch_bounds__(256) void node_emb_kernel(
    const float* __restrict__ x, const float* __restrict__ pos,
    const float* __restrict__ Wa, const float* __restrict__ ba,
    const float* __restrict__ Wp, const float* __restrict__ bp,
    _Float16* __restrict__ nodeEmb, int N)
{
    __shared__ __align__(16) _Float16 sOut[64 * LDO];   // 17 KB
    const int t    = threadIdx.x;
    const int wave = t >> 6;
    const int lane = t & 63;
    const int quad = lane >> 4;
    const int l16  = lane & 15;

    half8 wf[2];
    floatx4 bias[2];
    #pragma unroll
    for (int ct = 0; ct < 2; ++ct) {
        int col = wave * 32 + ct * 16 + l16;
        #pragma unroll
        for (int j = 0; j < 8; ++j) {
            int k = quad * 8 + j;
            float w = 0.f;
            if (k < 16) w = Wa[k * HID + col];
            else if (k < 19) w = Wp[(k - 16) * HID + col];
            wf[ct][j] = (_Float16)w;
        }
        #pragma unroll
        for (int i = 0; i < 4; ++i) {
            int c2 = wave * 32 + ct * 16 + quad * 4 + i;
            bias[ct][i] = ba[c2] + bp[c2];
        }
    }

    int nTiles = (N + 63) >> 6;
    for (int tile = blockIdx.x; tile < nTiles; tile += gridDim.x) {
        int base = tile * 64;
        half8 af[4];
        #pragma unroll
        for (int rt = 0; rt < 4; ++rt) {
            int node = base + rt * 16 + l16;
            int nd = node < N ? node : N - 1;
            half8 a = (half8){0, 0, 0, 0, 0, 0, 0, 0};
            if (quad < 2) {
                const float* xp = x + (size_t)nd * 16 + quad * 8;
                float4 v0 = *(const float4*)xp;
                float4 v1 = *(const float4*)(xp + 4);
                a[0] = (_Float16)v0.x; a[1] = (_Float16)v0.y;
                a[2] = (_Float16)v0.z; a[3] = (_Float16)v0.w;
                a[4] = (_Float16)v1.x; a[5] = (_Float16)v1.y;
                a[6] = (_Float16)v1.z; a[7] = (_Float16)v1.w;
            } else if (quad == 2) {
                const float* pp = pos + (size_t)nd * 3;
                a[0] = (_Float16)pp[0]; a[1] = (_Float16)pp[1]; a[2] = (_Float16)pp[2];
            }
            af[rt] = a;
        }
        #pragma unroll
        for (int ct = 0; ct < 2; ++ct)
            #pragma unroll
            for (int rt = 0; rt < 4; ++rt) {
                floatx4 d = bias[ct];
                d = __builtin_amdgcn_mfma_f32_16x16x32_f16(wf[ct], af[rt], d, 0, 0, 0);
                half4 hv;
                hv[0] = (_Float16)d[0]; hv[1] = (_Float16)d[1];
                hv[2] = (_Float16)d[2]; hv[3] = (_Float16)d[3];
                *(half4*)&sOut[(rt * 16 + l16) * LDO + wave * 32 + ct * 16 + quad * 4] = hv;
            }
        __syncthreads();
        #pragma unroll
        for (int p = 0; p < 4; ++p) {
            int idx = p * 256 + t;
            int r = idx >> 4, c = idx & 15;
            int node = base + r;
            if (node < N)
                *(half8*)(nodeEmb + (size_t)node * HID + c * 8) =
                    *(const half8*)&sOut[r * LDO + c * 8];
        }
        __syncthreads();
    }
}

// ---------------------------------------------------------------------------
// Kernel 2: per-edge MLP. Round-0 structure (2 blocks/CU, VGPR ~128, all
// weight fragments in registers) + DOUBLE-BUFFERED A-tile with h1/h2 living
// inside the consumed A-buffer:
//   buf[cur]   : A-data(T) [32 KB] -> after layer-1 (B1.75) becomes
//                h1 [first 16 KB] then h2 [second 16 KB]
//   buf[cur^1] : h2(T-1) [2nd half, read by L3 after B1] ; then DMA(T+1)
//                target, issued right after B1.75 (gets epi1+L2+epi2 cover
//                instead of round-0's post-B2 issue with only L2+epi2 cover)
// Hazards: B1 (syncthreads) drains DMA(T)+h2 writes; B1.75 (lds-only) drains
// ALL waves' L3 reads of buf[cur^1] and layer-1 reads of buf[cur] before
// DMA(T+1) / h1-writes touch them; B2 (lds-only) publishes h1. epi-2's h2
// region is disjoint from layer-2's h1 reads -> no barrier needed between.
// LDS = 64 KB + sDist = 66048 reported -> 2 blocks/CU (same as round-0).
// ---------------------------------------------------------------------------
__global__ __launch_bounds__(256, 2) void edge_mlp_kernel(
    const _Float16* __restrict__ nodeEmb,
    const float* __restrict__ pos,
    const int* __restrict__ eidx,          // [2][E]
    const float* __restrict__ W1, const float* __restrict__ b1,   // [257][128]
    const float* __restrict__ W2, const float* __restrict__ b2,   // [128][128]
    const float* __restrict__ W3, const float* __restrict__ b3,   // [128][4]
    float* __restrict__ out, int E, int nTiles)
{
    __shared__ __align__(16) _Float16 sA[2 * TSZ];   // 64 KB: two A-tile buffers
    __shared__ float sDist[TILE_M];

    const int t    = threadIdx.x;
    const int wave = t >> 6;
    const int lane = t & 63;
    const int quad = lane >> 4;
    const int l16  = lane & 15;
    const int colbase = wave * 32;        // each wave owns 32 output columns

    // ---- weight fragments (frag[j] = W[k0+quad*8+j][col]) ----
    half8 w1f[8][2];
    half8 w2f[4][2];
    half8 w3f[4];
    float w1c[2][4], b1f[2][4], b2f[2][4];
    #pragma unroll
    for (int ct = 0; ct < 2; ++ct) {
        int col = colbase + ct * 16 + l16;
        #pragma unroll
        for (int kc = 0; kc < 8; ++kc)
            #pragma unroll
            for (int j = 0; j < 8; ++j)
                w1f[kc][ct][j] = (_Float16)W1[(kc * 32 + quad * 8 + j) * HID + col];
        #pragma unroll
        for (int kc = 0; kc < 4; ++kc)
            #pragma unroll
            for (int j = 0; j < 8; ++j)
                w2f[kc][ct][j] = (_Float16)W2[(kc * 32 + quad * 8 + j) * HID + col];
        #pragma unroll
        for (int i = 0; i < 4; ++i) {
            int c2 = colbase + ct * 16 + quad * 4 + i;
            w1c[ct][i] = W1[256 * HID + c2];
            b1f[ct][i] = b1[c2];
            b2f[ct][i] = b2[c2];
        }
    }
    #pragma unroll
    for (int kc = 0; kc < 4; ++kc)
        #pragma unroll
        for (int j = 0; j < 8; ++j)
            w3f[kc][j] = (_Float16)W3[(kc * 32 + quad * 8 + j) * 4 + (l16 & 3)];
    const float b3v0 = b3[0], b3v1 = b3[1], b3v2 = b3[2], b3v3 = b3[3];

    int nid[8];
    float dpre = 0.f;

    auto load_nid = [&](int tl) {
        int eb = tl * TILE_M;
        #pragma unroll
        for (int i = 0; i < 8; ++i) {
            int cid = i * 256 + t;           // 0..2047 chunks of 16B
            int row = cid >> 4;              // 0..127: 0-63 src, 64-127 dst
            int r   = row & 63;
            int e   = eb + r; if (e >= E) e = E - 1;
            nid[i] = (row >> 6) ? eidx[(size_t)E + e] : eidx[e];
        }
    };
    auto load_dist = [&](int tl) -> float {
        if (t >= TILE_M) return 0.f;
        int e = tl * TILE_M + t; if (e >= E) e = E - 1;
        int s = eidx[e], d = eidx[(size_t)E + e];
        float dx = pos[3 * (size_t)s]     - pos[3 * (size_t)d];
        float dy = pos[3 * (size_t)s + 1] - pos[3 * (size_t)d + 1];
        float dz = pos[3 * (size_t)s + 2] - pos[3 * (size_t)d + 2];
        return sqrtf(dx * dx + dy * dy + dz * dz);
    };
    auto dma_issue = [&](_Float16* dst) {
        #pragma unroll
        for (int i = 0; i < 8; ++i) {
            int cid = i * 256 + t;
            int row = cid >> 4;
            int cg  = (cid & 15) ^ (row & 15);      // XOR swizzle
            const _Float16* gp = nodeEmb + (size_t)nid[i] * HID + cg * 8;
            __builtin_amdgcn_global_load_lds(
                (__attribute__((address_space(1))) void*)gp,
                (__attribute__((address_space(3))) void*)&dst[(i * 256 + (t & 192)) * 8],
                16, 0, 0);
        }
    };

    bool havePrev = false;
    int prevEbase = 0;
    int cur = 0;
    int prevBuf = 0;
    int tile = blockIdx.x;
    if (tile < nTiles) {
        load_nid(tile);
        dpre = load_dist(tile);
        dma_issue(sA);                       // tile0 -> buf0; drains at first B1
    }

    for (; tile < nTiles; tile += gridDim.x) {
        const int ebase = tile * TILE_M;
        _Float16* bufC = sA + cur * TSZ;          // A(T), then h1/h2(T)
        _Float16* bufP = sA + (cur ^ 1) * TSZ;    // h2(T-1) in 2nd half; DMA(T+1) tgt
        if (t < TILE_M) sDist[t] = dpre;
        __syncthreads();                     // B1: DMA(T) drained, h2(T-1) ready

        // ---- layer 3 of previous tile: MFMA from bufP 2nd half, store ----
        if (havePrev) {
            floatx4 acc3 = (floatx4){0.f, 0.f, 0.f, 0.f};
            #pragma unroll
            for (int kc = 0; kc < 4; ++kc) {
                int slot = ((kc * 4 + quad) ^ l16) * 8;
                half8 h = *(const half8*)&bufP[H2OFF + (wave * 16 + l16) * HID + slot];
                acc3 = __builtin_amdgcn_mfma_f32_16x16x32_f16(w3f[kc], h, acc3, 0, 0, 0);
            }
            if (quad == 0) {
                int e = prevEbase + wave * 16 + l16;
                if (e < E) {
                    float4 o = {acc3[0] + b3v0, acc3[1] + b3v1,
                                acc3[2] + b3v2, acc3[3] + b3v3};
                    *(float4*)&out[(size_t)e * 4] = o;
                }
            }
        }

        // ---- prefetch next tile metadata (consumed at dma_issue post-B1.75;
        //      layer-1 covers the load latency) ----
        int nxt = tile + gridDim.x;
        if (nxt < nTiles) {
            load_nid(nxt);
            dpre = load_dist(nxt);
        }

        // ---- layer 1: bias in acc init, XOR-swizzled bufC reads ----
        floatx4 acc[2][4];
        #pragma unroll
        for (int ct = 0; ct < 2; ++ct)
            #pragma unroll
            for (int rt = 0; rt < 4; ++rt) {
                acc[ct][rt][0] = b1f[ct][0]; acc[ct][rt][1] = b1f[ct][1];
                acc[ct][rt][2] = b1f[ct][2]; acc[ct][rt][3] = b1f[ct][3];
            }
        #pragma unroll
        for (int kc = 0; kc < 8; ++kc) {
            int hf   = kc >> 2;
            int cg   = (kc & 3) * 4 + quad;
            int slot = (cg ^ l16) * 8;
            const _Float16* base = &bufC[(hf * TILE_M + l16) * HID + slot];
            half8 a0 = *(const half8*)(base + 0 * 16 * HID);
            half8 a1 = *(const half8*)(base + 1 * 16 * HID);
            half8 a2 = *(const half8*)(base + 2 * 16 * HID);
            half8 a3 = *(const half8*)(base + 3 * 16 * HID);
            acc[0][0] = __builtin_amdgcn_mfma_f32_16x16x32_f16(w1f[kc][0], a0, acc[0][0], 0, 0, 0);
            acc[0][1] = __builtin_amdgcn_mfma_f32_16x16x32_f16(w1f[kc][0], a1, acc[0][1], 0, 0, 0);
            acc[0][2] = __builtin_amdgcn_mfma_f32_16x16x32_f16(w1f[kc][0], a2, acc[0][2], 0, 0, 0);
            acc[0][3] = __builtin_amdgcn_mfma_f32_16x16x32_f16(w1f[kc][0], a3, acc[0][3], 0, 0, 0);
            acc[1][0] = __builtin_amdgcn_mfma_f32_16x16x32_f16(w1f[kc][1], a0, acc[1][0], 0, 0, 0);
            acc[1][1] = __builtin_amdgcn_mfma_f32_16x16x32_f16(w1f[kc][1], a1, acc[1][1], 0, 0, 0);
            acc[1][2] = __builtin_amdgcn_mfma_f32_16x16x32_f16(w1f[kc][1], a2, acc[1][2], 0, 0, 0);
            acc[1][3] = __builtin_amdgcn_mfma_f32_16x16x32_f16(w1f[kc][1], a3, acc[1][3], 0, 0, 0);
        }
        // B1.75: ALL waves done reading bufC (layer-1) and bufP (L3).
        // lgkm-only: prefetch global loads stay in flight.
        barrier_lds_only();

        // ---- async DMA for next tile into bufP (now fully dead).
        //      Cover: epi-1 + B2 + layer-2 + epi-2 + next B1. ----
        if (nxt < nTiles) dma_issue(bufP);

        // epilogue 1 -> h1 in bufC 1st half (XOR-swizzled uint2 writes)
        #pragma unroll
        for (int rt = 0; rt < 4; ++rt) {
            int m = rt * 16 + l16;
            float d = sDist[m];
            #pragma unroll
            for (int ct = 0; ct < 2; ++ct) {
                float v0 = fast_silu(fmaf(d, w1c[ct][0], acc[ct][rt][0]));
                float v1 = fast_silu(fmaf(d, w1c[ct][1], acc[ct][rt][1]));
                float v2 = fast_silu(fmaf(d, w1c[ct][2], acc[ct][rt][2]));
                float v3 = fast_silu(fmaf(d, w1c[ct][3], acc[ct][rt][3]));
                uint2 w;
                w.x = pk2(v0, v1);
                w.y = pk2(v2, v3);
                int cgb  = wave * 4 + ct * 2 + (quad >> 1);
                int slot = cgb ^ l16;
                *(uint2*)&bufC[m * HID + slot * 8 + (quad & 1) * 4] = w;
            }
        }
        barrier_lds_only();                  // B2: h1 visible; DMA loads live

        // ---- layer 2: reads h1 from bufC 1st half ----
        floatx4 acc2[2][4];
        #pragma unroll
        for (int ct = 0; ct < 2; ++ct)
            #pragma unroll
            for (int rt = 0; rt < 4; ++rt) {
                acc2[ct][rt][0] = b2f[ct][0]; acc2[ct][rt][1] = b2f[ct][1];
                acc2[ct][rt][2] = b2f[ct][2]; acc2[ct][rt][3] = b2f[ct][3];
            }
        #pragma unroll
        for (int kc = 0; kc < 4; ++kc) {
            int slot = ((kc * 4 + quad) ^ l16) * 8;
            half8 a0 = *(const half8*)&bufC[(0 * 16 + l16) * HID + slot];
            half8 a1 = *(const half8*)&bufC[(1 * 16 + l16) * HID + slot];
            half8 a2 = *(const half8*)&bufC[(2 * 16 + l16) * HID + slot];
            half8 a3 = *(const half8*)&bufC[(3 * 16 + l16) * HID + slot];
            acc2[0][0] = __builtin_amdgcn_mfma_f32_16x16x32_f16(w2f[kc][0], a0, acc2[0][0], 0, 0, 0);
            acc2[0][1] = __builtin_amdgcn_mfma_f32_16x16x32_f16(w2f[kc][0], a1, acc2[0][1], 0, 0, 0);
            acc2[0][2] = __builtin_amdgcn_mfma_f32_16x16x32_f16(w2f[kc][0], a2, acc2[0][2], 0, 0, 0);
            acc2[0][3] = __builtin_amdgcn_mfma_f32_16x16x32_f16(w2f[kc][0], a3, acc2[0][3], 0, 0, 0);
            acc2[1][0] = __builtin_amdgcn_mfma_f32_16x16x32_f16(w2f[kc][1], a0, acc2[1][0], 0, 0, 0);
            acc2[1][1] = __builtin_amdgcn_mfma_f32_16x16x32_f16(w2f[kc][1], a1, acc2[1][1], 0, 0, 0);
            acc2[1][2] = __builtin_amdgcn_mfma_f32_16x16x32_f16(w2f[kc][1], a2, acc2[1][2], 0, 0, 0);
            acc2[1][3] = __builtin_amdgcn_mfma_f32_16x16x32_f16(w2f[kc][1], a3, acc2[1][3], 0, 0, 0);
        }

        // epilogue 2 -> h2 in bufC 2nd half (disjoint from h1 reads above:
        // no barrier needed; old contents were A-rows 64-127, dead since B1.75)
        #pragma unroll
        for (int rt = 0; rt < 4; ++rt) {
            int m = rt * 16 + l16;
            #pragma unroll
            for (int ct = 0; ct < 2; ++ct) {
                float v0 = fast_silu(acc2[ct][rt][0]);
                float v1 = fast_silu(acc2[ct][rt][1]);
                float v2 = fast_silu(acc2[ct][rt][2]);
                float v3 = fast_silu(acc2[ct][rt][3]);
                uint2 w;
                w.x = pk2(v0, v1);
                w.y = pk2(v2, v3);
                int cgb  = wave * 4 + ct * 2 + (quad >> 1);
                int slot = cgb ^ l16;
                *(uint2*)&bufC[H2OFF + m * HID + slot * 8 + (quad & 1) * 4] = w;
            }
        }
        havePrev = true;
        prevEbase = ebase;
        prevBuf = cur;
        cur ^= 1;
    }

    // ---- flush: layer 3 of the final tile ----
    if (havePrev) {
        __syncthreads();
        const _Float16* bufL = sA + prevBuf * TSZ;
        floatx4 acc3 = (floatx4){0.f, 0.f, 0.f, 0.f};
        #pragma unroll
        for (int kc = 0; kc < 4; ++kc) {
            int slot = ((kc * 4 + quad) ^ l16) * 8;
            half8 h = *(const half8*)&bufL[H2OFF + (wave * 16 + l16) * HID + slot];
            acc3 = __builtin_amdgcn_mfma_f32_16x16x32_f16(w3f[kc], h, acc3, 0, 0, 0);
        }
        if (quad == 0) {
            int e = prevEbase + wave * 16 + l16;
            if (e < E) {
                float4 o = {acc3[0] + b3v0, acc3[1] + b3v1,
                            acc3[2] + b3v2, acc3[3] + b3v3};
                *(float4*)&out[(size_t)e * 4] = o;
            }
        }
    }
}

extern "C" void kernel_launch(void* const* d_in, const int* in_sizes, int n_in,
                              void* d_out, int out_size, void* d_ws, size_t ws_size,
                              hipStream_t stream) {
    const float* x   = (const float*)d_in[0];
    const float* pos = (const float*)d_in[1];
    const int*  eidx = (const int*)d_in[2];
    const float* Wa = (const float*)d_in[3];
    const float* ba = (const float*)d_in[4];
    const float* Wp = (const float*)d_in[5];
    const float* bp = (const float*)d_in[6];
    const float* W1 = (const float*)d_in[7];
    const float* b1 = (const float*)d_in[8];
    const float* W2 = (const float*)d_in[9];
    const float* b2 = (const float*)d_in[10];
    const float* W3 = (const float*)d_in[11];
    const float* b3 = (const float*)d_in[12];
    float* out = (float*)d_out;

    int N = in_sizes[0] / 16;   // ATOM_DIM
    int E = in_sizes[2] / 2;

    _Float16* nodeEmb = (_Float16*)d_ws;   // N*128 fp16 = 25.6 MB

    int nodeTiles = (N + 63) / 64;
    node_emb_kernel<<<nodeTiles, 256, 0, stream>>>(x, pos, Wa, ba, Wp, bp, nodeEmb, N);

    int nTiles = (E + TILE_M - 1) / TILE_M;
    // 2 blocks/CU x 256 CUs
    edge_mlp_kernel<<<512, 256, 0, stream>>>(nodeEmb, pos, eidx,
                                             W1, b1, W2, b2, W3, b3,
                                             out, E, nTiles);
}

// Round 6
// 330.251 us; speedup vs baseline: 1.7784x; 1.0764x over previous
//
#include <hip/hip_runtime.h>
#include <hip/hip_bf16.h>
#include <hip/hip_fp16.h>

typedef _Float16 half8 __attribute__((ext_vector_type(8)));
typedef _Float16 half4 __attribute__((ext_vector_type(4)));
typedef __fp16 fp16x2 __attribute__((ext_vector_type(2)));
typedef float floatx4 __attribute__((ext_vector_type(4)));

#define HID 128
#define TILE_M 64

__device__ __forceinline__ float fast_silu(float v) {
    float e = __expf(-v);
    return v * __builtin_amdgcn_rcpf(1.f + e);
}

__device__ __forceinline__ unsigned int pk2(float a, float b) {
    fp16x2 h = __builtin_amdgcn_cvt_pkrtz(a, b);
    return __builtin_bit_cast(unsigned int, h);
}

// LDS-only barrier: drains LDS ops but leaves global (vmcnt) traffic in
// flight. Use ONLY where the barrier guards LDS-LDS hazards exclusively.
__device__ __forceinline__ void barrier_lds_only() {
    asm volatile("s_waitcnt lgkmcnt(0)\n\ts_barrier" ::: "memory");
}

// ---------------------------------------------------------------------------
// Kernel 1: node_emb = [x|pos|0-pad] @ [Wa;Wp;0] + (ba+bp). Block handles a
// 64-node tile via MFMA; output assembled in padded LDS, stored coalesced.
// ---------------------------------------------------------------------------
#define LDO 136
__global__ __launch_bounds__(256) void node_emb_kernel(
    const float* __restrict__ x, const float* __restrict__ pos,
    const float* __restrict__ Wa, const float* __restrict__ ba,
    const float* __restrict__ Wp, const float* __restrict__ bp,
    _Float16* __restrict__ nodeEmb, int N)
{
    __shared__ __align__(16) _Float16 sOut[64 * LDO];   // 17 KB
    const int t    = threadIdx.x;
    const int wave = t >> 6;
    const int lane = t & 63;
    const int quad = lane >> 4;
    const int l16  = lane & 15;

    half8 wf[2];
    floatx4 bias[2];
    #pragma unroll
    for (int ct = 0; ct < 2; ++ct) {
        int col = wave * 32 + ct * 16 + l16;
        #pragma unroll
        for (int j = 0; j < 8; ++j) {
            int k = quad * 8 + j;
            float w = 0.f;
            if (k < 16) w = Wa[k * HID + col];
            else if (k < 19) w = Wp[(k - 16) * HID + col];
            wf[ct][j] = (_Float16)w;
        }
        #pragma unroll
        for (int i = 0; i < 4; ++i) {
            int c2 = wave * 32 + ct * 16 + quad * 4 + i;
            bias[ct][i] = ba[c2] + bp[c2];
        }
    }

    int nTiles = (N + 63) >> 6;
    for (int tile = blockIdx.x; tile < nTiles; tile += gridDim.x) {
        int base = tile * 64;
        half8 af[4];
        #pragma unroll
        for (int rt = 0; rt < 4; ++rt) {
            int node = base + rt * 16 + l16;
            int nd = node < N ? node : N - 1;
            half8 a = (half8){0, 0, 0, 0, 0, 0, 0, 0};
            if (quad < 2) {
                const float* xp = x + (size_t)nd * 16 + quad * 8;
                float4 v0 = *(const float4*)xp;
                float4 v1 = *(const float4*)(xp + 4);
                a[0] = (_Float16)v0.x; a[1] = (_Float16)v0.y;
                a[2] = (_Float16)v0.z; a[3] = (_Float16)v0.w;
                a[4] = (_Float16)v1.x; a[5] = (_Float16)v1.y;
                a[6] = (_Float16)v1.z; a[7] = (_Float16)v1.w;
            } else if (quad == 2) {
                const float* pp = pos + (size_t)nd * 3;
                a[0] = (_Float16)pp[0]; a[1] = (_Float16)pp[1]; a[2] = (_Float16)pp[2];
            }
            af[rt] = a;
        }
        #pragma unroll
        for (int ct = 0; ct < 2; ++ct)
            #pragma unroll
            for (int rt = 0; rt < 4; ++rt) {
                floatx4 d = bias[ct];
                d = __builtin_amdgcn_mfma_f32_16x16x32_f16(wf[ct], af[rt], d, 0, 0, 0);
                half4 hv;
                hv[0] = (_Float16)d[0]; hv[1] = (_Float16)d[1];
                hv[2] = (_Float16)d[2]; hv[3] = (_Float16)d[3];
                *(half4*)&sOut[(rt * 16 + l16) * LDO + wave * 32 + ct * 16 + quad * 4] = hv;
            }
        __syncthreads();
        #pragma unroll
        for (int p = 0; p < 4; ++p) {
            int idx = p * 256 + t;
            int r = idx >> 4, c = idx & 15;
            int node = base + r;
            if (node < N)
                *(half8*)(nodeEmb + (size_t)node * HID + c * 8) =
                    *(const half8*)&sOut[r * LDO + c * 8];
        }
        __syncthreads();
    }
}

// ---------------------------------------------------------------------------
// Kernel 2: per-edge MLP. 512 threads = 8 waves x 16 output cols each
// (was 4 waves x 32 cols). Halving the per-wave column slice halves the
// register-hungry state: w1f 64->32, w2f 32->16, acc 32->16, acc2 32->16,
// w3f -> sW3 LDS table. Peak demand ~120 VGPR -> fits the 128-reg cap of
// 4 waves/SIMD: launch_bounds(512,4) => 2 blocks/CU x 8 waves = 16 waves/CU
// (2x round-0's occupancy) with NO spill and NO weight streaming — the two
// handicaps that poisoned rounds 1/3/4's occupancy experiments.
// Same round-0 single-sA 2-barrier pipeline; all row/col index math is
// wave-count-agnostic. LDS 65.5 KB -> 2 blocks/CU (LDS-feasible up to 2).
// Verify: VGPR<=128 & WRITE_SIZE ~42 MB (no spill), Occupancy ~42%.
// ---------------------------------------------------------------------------
__global__ __launch_bounds__(512, 4) void edge_mlp_kernel(
    const _Float16* __restrict__ nodeEmb,
    const float* __restrict__ pos,
    const int* __restrict__ eidx,          // [2][E]
    const float* __restrict__ W1, const float* __restrict__ b1,   // [257][128]
    const float* __restrict__ W2, const float* __restrict__ b2,   // [128][128]
    const float* __restrict__ W3, const float* __restrict__ b3,   // [128][4]
    float* __restrict__ out, int E, int nTiles)
{
    __shared__ __align__(16) _Float16 sA[2 * TILE_M * HID];   // 32 KB, XOR swizzle
    __shared__ __align__(16) _Float16 sH1[TILE_M * HID];      // 16 KB, XOR swizzle
    __shared__ __align__(16) _Float16 sH2[TILE_M * HID];      // 16 KB, XOR swizzle
    __shared__ float sDist[TILE_M];
    __shared__ __align__(16) _Float16 sW3[512];               // 1 KB  W3 frags

    const int t    = threadIdx.x;
    const int wave = t >> 6;               // 0..7
    const int lane = t & 63;
    const int quad = lane >> 4;
    const int l16  = lane & 15;
    const int colbase = wave * 16;         // each wave owns 16 output columns

    // ---- stage W3 fragment table into LDS (consumed after first B1) ----
    if (t < 64) {
        int kc = t >> 4, q = (t >> 2) & 3, c = t & 3;
        #pragma unroll
        for (int j = 0; j < 8; ++j)
            sW3[(kc * 16 + q * 4 + c) * 8 + j] =
                (_Float16)W3[(kc * 32 + q * 8 + j) * 4 + c];
    }

    // ---- weight fragments (frag[j] = W[k0+quad*8+j][col]), 1 col-tile/wave ----
    half8 w1f[8];                          // 32 VGPR
    half8 w2f[4];                          // 16 VGPR
    float w1c[4], b1f[4], b2f[4];
    {
        int col = colbase + l16;
        #pragma unroll
        for (int kc = 0; kc < 8; ++kc)
            #pragma unroll
            for (int j = 0; j < 8; ++j)
                w1f[kc][j] = (_Float16)W1[(kc * 32 + quad * 8 + j) * HID + col];
        #pragma unroll
        for (int kc = 0; kc < 4; ++kc)
            #pragma unroll
            for (int j = 0; j < 8; ++j)
                w2f[kc][j] = (_Float16)W2[(kc * 32 + quad * 8 + j) * HID + col];
        #pragma unroll
        for (int i = 0; i < 4; ++i) {
            int c2 = colbase + quad * 4 + i;
            w1c[i] = W1[256 * HID + c2];
            b1f[i] = b1[c2];
            b2f[i] = b2[c2];
        }
    }
    const float b3v0 = b3[0], b3v1 = b3[1], b3v2 = b3[2], b3v3 = b3[3];

    int nid[4];
    float dpre = 0.f;

    auto load_nid = [&](int tl) {
        int eb = tl * TILE_M;
        #pragma unroll
        for (int i = 0; i < 4; ++i) {
            int cid = i * 512 + t;           // 0..2047 chunks of 16B
            int row = cid >> 4;              // 0..127: 0-63 src, 64-127 dst
            int r   = row & 63;
            int e   = eb + r; if (e >= E) e = E - 1;
            nid[i] = (row >> 6) ? eidx[(size_t)E + e] : eidx[e];
        }
    };
    auto load_dist = [&](int tl) -> float {
        if (t >= TILE_M) return 0.f;
        int e = tl * TILE_M + t; if (e >= E) e = E - 1;
        int s = eidx[e], d = eidx[(size_t)E + e];
        float dx = pos[3 * (size_t)s]     - pos[3 * (size_t)d];
        float dy = pos[3 * (size_t)s + 1] - pos[3 * (size_t)d + 1];
        float dz = pos[3 * (size_t)s + 2] - pos[3 * (size_t)d + 2];
        return sqrtf(dx * dx + dy * dy + dz * dz);
    };
    auto dma_issue = [&]() {
        #pragma unroll
        for (int i = 0; i < 4; ++i) {
            int cid = i * 512 + t;
            int row = cid >> 4;
            int cg  = (cid & 15) ^ (row & 15);      // XOR swizzle
            const _Float16* gp = nodeEmb + (size_t)nid[i] * HID + cg * 8;
            __builtin_amdgcn_global_load_lds(
                (__attribute__((address_space(1))) void*)gp,
                (__attribute__((address_space(3))) void*)&sA[(i * 512 + (t & 448)) * 8],
                16, 0, 0);
        }
    };

    bool havePrev = false;
    int prevEbase = 0;
    int tile = blockIdx.x;
    if (tile < nTiles) {
        load_nid(tile);
        dpre = load_dist(tile);
        dma_issue();                         // drains at first B1
    }

    for (; tile < nTiles; tile += gridDim.x) {
        const int ebase = tile * TILE_M;
        if (t < TILE_M) sDist[t] = dpre;
        __syncthreads();                     // B1: DMA(T) drained, sH2(T-1) ready

        // ---- layer 3 of previous tile: waves 0-3 cover the 64 edges ----
        if (havePrev && wave < 4) {
            floatx4 acc3 = (floatx4){0.f, 0.f, 0.f, 0.f};
            #pragma unroll
            for (int kc = 0; kc < 4; ++kc) {
                int slot = ((kc * 4 + quad) ^ l16) * 8;
                half8 h  = *(const half8*)&sH2[(wave * 16 + l16) * HID + slot];
                half8 w3 = *(const half8*)&sW3[(kc * 16 + quad * 4 + (l16 & 3)) * 8];
                acc3 = __builtin_amdgcn_mfma_f32_16x16x32_f16(w3, h, acc3, 0, 0, 0);
            }
            if (quad == 0) {
                int e = prevEbase + wave * 16 + l16;
                if (e < E) {
                    float4 o = {acc3[0] + b3v0, acc3[1] + b3v1,
                                acc3[2] + b3v2, acc3[3] + b3v3};
                    *(float4*)&out[(size_t)e * 4] = o;
                }
            }
        }

        // ---- prefetch next tile metadata (DMA issued post-B2) ----
        int nxt = tile + gridDim.x;
        if (nxt < nTiles) {
            load_nid(nxt);
            dpre = load_dist(nxt);
        }

        // ---- layer 1: bias in acc init, XOR-swizzled sA reads ----
        floatx4 acc[4];
        #pragma unroll
        for (int rt = 0; rt < 4; ++rt) {
            acc[rt][0] = b1f[0]; acc[rt][1] = b1f[1];
            acc[rt][2] = b1f[2]; acc[rt][3] = b1f[3];
        }
        #pragma unroll
        for (int kc = 0; kc < 8; ++kc) {
            int hf   = kc >> 2;
            int cg   = (kc & 3) * 4 + quad;
            int slot = (cg ^ l16) * 8;
            const _Float16* base = &sA[(hf * TILE_M + l16) * HID + slot];
            half8 a0 = *(const half8*)(base + 0 * 16 * HID);
            half8 a1 = *(const half8*)(base + 1 * 16 * HID);
            half8 a2 = *(const half8*)(base + 2 * 16 * HID);
            half8 a3 = *(const half8*)(base + 3 * 16 * HID);
            acc[0] = __builtin_amdgcn_mfma_f32_16x16x32_f16(w1f[kc], a0, acc[0], 0, 0, 0);
            acc[1] = __builtin_amdgcn_mfma_f32_16x16x32_f16(w1f[kc], a1, acc[1], 0, 0, 0);
            acc[2] = __builtin_amdgcn_mfma_f32_16x16x32_f16(w1f[kc], a2, acc[2], 0, 0, 0);
            acc[3] = __builtin_amdgcn_mfma_f32_16x16x32_f16(w1f[kc], a3, acc[3], 0, 0, 0);
        }
        // epilogue 1 -> sH1 (XOR-swizzled uint2 writes)
        #pragma unroll
        for (int rt = 0; rt < 4; ++rt) {
            int m = rt * 16 + l16;
            float d = sDist[m];
            float v0 = fast_silu(fmaf(d, w1c[0], acc[rt][0]));
            float v1 = fast_silu(fmaf(d, w1c[1], acc[rt][1]));
            float v2 = fast_silu(fmaf(d, w1c[2], acc[rt][2]));
            float v3 = fast_silu(fmaf(d, w1c[3], acc[rt][3]));
            uint2 w;
            w.x = pk2(v0, v1);
            w.y = pk2(v2, v3);
            int cgb  = wave * 2 + (quad >> 1);
            int slot = cgb ^ l16;
            *(uint2*)&sH1[m * HID + slot * 8 + (quad & 1) * 4] = w;
        }
        barrier_lds_only();                  // B2: LDS-only; prefetch loads live

        // ---- async DMA for next tile (sA free; overlaps L2+L3+next B1) ----
        if (nxt < nTiles) dma_issue();

        // ---- layer 2 ----
        floatx4 acc2[4];
        #pragma unroll
        for (int rt = 0; rt < 4; ++rt) {
            acc2[rt][0] = b2f[0]; acc2[rt][1] = b2f[1];
            acc2[rt][2] = b2f[2]; acc2[rt][3] = b2f[3];
        }
        #pragma unroll
        for (int kc = 0; kc < 4; ++kc) {
            int slot = ((kc * 4 + quad) ^ l16) * 8;
            half8 a0 = *(const half8*)&sH1[(0 * 16 + l16) * HID + slot];
            half8 a1 = *(const half8*)&sH1[(1 * 16 + l16) * HID + slot];
            half8 a2 = *(const half8*)&sH1[(2 * 16 + l16) * HID + slot];
            half8 a3 = *(const half8*)&sH1[(3 * 16 + l16) * HID + slot];
            acc2[0] = __builtin_amdgcn_mfma_f32_16x16x32_f16(w2f[kc], a0, acc2[0], 0, 0, 0);
            acc2[1] = __builtin_amdgcn_mfma_f32_16x16x32_f16(w2f[kc], a1, acc2[1], 0, 0, 0);
            acc2[2] = __builtin_amdgcn_mfma_f32_16x16x32_f16(w2f[kc], a2, acc2[2], 0, 0, 0);
            acc2[3] = __builtin_amdgcn_mfma_f32_16x16x32_f16(w2f[kc], a3, acc2[3], 0, 0, 0);
        }
        // epilogue 2 -> sH2 (all waves' L3(T-1) reads finished before B2)
        #pragma unroll
        for (int rt = 0; rt < 4; ++rt) {
            int m = rt * 16 + l16;
            float v0 = fast_silu(acc2[rt][0]);
            float v1 = fast_silu(acc2[rt][1]);
            float v2 = fast_silu(acc2[rt][2]);
            float v3 = fast_silu(acc2[rt][3]);
            uint2 w;
            w.x = pk2(v0, v1);
            w.y = pk2(v2, v3);
            int cgb  = wave * 2 + (quad >> 1);
            int slot = cgb ^ l16;
            *(uint2*)&sH2[m * HID + slot * 8 + (quad & 1) * 4] = w;
        }
        havePrev = true;
        prevEbase = ebase;
    }

    // ---- flush: layer 3 of the final tile ----
    if (havePrev) {
        __syncthreads();
        if (wave < 4) {
            floatx4 acc3 = (floatx4){0.f, 0.f, 0.f, 0.f};
            #pragma unroll
            for (int kc = 0; kc < 4; ++kc) {
                int slot = ((kc * 4 + quad) ^ l16) * 8;
                half8 h  = *(const half8*)&sH2[(wave * 16 + l16) * HID + slot];
                half8 w3 = *(const half8*)&sW3[(kc * 16 + quad * 4 + (l16 & 3)) * 8];
                acc3 = __builtin_amdgcn_mfma_f32_16x16x32_f16(w3, h, acc3, 0, 0, 0);
            }
            if (quad == 0) {
                int e = prevEbase + wave * 16 + l16;
                if (e < E) {
                    float4 o = {acc3[0] + b3v0, acc3[1] + b3v1,
                                acc3[2] + b3v2, acc3[3] + b3v3};
                    *(float4*)&out[(size_t)e * 4] = o;
                }
            }
        }
    }
}

extern "C" void kernel_launch(void* const* d_in, const int* in_sizes, int n_in,
                              void* d_out, int out_size, void* d_ws, size_t ws_size,
                              hipStream_t stream) {
    const float* x   = (const float*)d_in[0];
    const float* pos = (const float*)d_in[1];
    const int*  eidx = (const int*)d_in[2];
    const float* Wa = (const float*)d_in[3];
    const float* ba = (const float*)d_in[4];
    const float* Wp = (const float*)d_in[5];
    const float* bp = (const float*)d_in[6];
    const float* W1 = (const float*)d_in[7];
    const float* b1 = (const float*)d_in[8];
    const float* W2 = (const float*)d_in[9];
    const float* b2 = (const float*)d_in[10];
    const float* W3 = (const float*)d_in[11];
    const float* b3 = (const float*)d_in[12];
    float* out = (float*)d_out;

    int N = in_sizes[0] / 16;   // ATOM_DIM
    int E = in_sizes[2] / 2;

    _Float16* nodeEmb = (_Float16*)d_ws;   // N*128 fp16 = 25.6 MB

    int nodeTiles = (N + 63) / 64;
    node_emb_kernel<<<nodeTiles, 256, 0, stream>>>(x, pos, Wa, ba, Wp, bp, nodeEmb, N);

    int nTiles = (E + TILE_M - 1) / TILE_M;
    // 2 blocks/CU x 256 CUs, 512 threads each
    edge_mlp_kernel<<<512, 512, 0, stream>>>(nodeEmb, pos, eidx,
                                             W1, b1, W2, b2, W3, b3,
                                             out, E, nTiles);
}